// Round 10
// baseline (83.461 us; speedup 1.0000x reference)
//
#include <hip/hip_runtime.h>
#include <math.h>

// LSH attention: B=2, H=8, S=2048, D=64, 6 bits -> 64 buckets, exact-match.
// Phase 1: bucket codes for Q and K (fused, sign of X.rot)
// Phase 2a: per-(side,bh) LDS histogram + wave shuffle-scan -> packed
//           kstart|cnt, q padded starts, placement cursors  (32 tiny blocks)
// Phase 2b: memset sentinel prefill of q_plist (hipMemsetAsync)
// Phase 2c: thread-per-element scatter via cursor atomics (order within a
//           bucket is arbitrary: query order affects nothing, key order only
//           ulp-level summation rounding)
// Phase 3: wave per 4 same-bucket queries (block-interleaved groups for load
//          balance); 32-key chunks, half-wave D-split scores, kv[8]-resident
//          K half-row; no-max softmax; lane=dim PV.

constexpr int S_LEN = 2048;
constexpr int D = 64;
constexpr int NHASH = 6;
constexpr int BH = 16;     // B*H
constexpr int NB = 64;     // 2^NHASH
constexpr int QPAD = 4;    // queries per wave
constexpr int PADQ = S_LEN + (QPAD - 1) * NB;   // 2240
constexpr int NGRP = PADQ / QPAD;               // 560 wave-groups per bh
constexpr int NBLK = NGRP / 4;                  // 140 blocks per bh (4 waves each)
constexpr int KCH = 32;    // key-chunk width (matches ~32-key buckets)

// ---- Phase 1: bucket codes for Q and K in one dispatch. One wave per vector.
__global__ __launch_bounds__(256) void lsh_buckets2(const float* __restrict__ Q,
                                                    const float* __restrict__ K,
                                                    const float* __restrict__ rot,
                                                    int* __restrict__ qb,
                                                    int* __restrict__ kb) {
    const int gw   = (blockIdx.x * 256 + threadIdx.x) >> 6;
    const int lane = threadIdx.x & 63;
    const bool isK = gw >= BH * S_LEN;
    const int wid  = isK ? gw - BH * S_LEN : gw;
    const float* X = isK ? K : Q;
    int* dst       = isK ? kb : qb;
    const int h    = (wid >> 11) & 7;

    const float x  = X[(size_t)wid * D + lane];
    const float* r = rot + (size_t)h * NHASH * D + lane;
    float p0 = x * r[0 * D], p1 = x * r[1 * D], p2 = x * r[2 * D];
    float p3 = x * r[3 * D], p4 = x * r[4 * D], p5 = x * r[5 * D];
#pragma unroll
    for (int off = 32; off >= 1; off >>= 1) {
        p0 += __shfl_xor(p0, off, 64);
        p1 += __shfl_xor(p1, off, 64);
        p2 += __shfl_xor(p2, off, 64);
        p3 += __shfl_xor(p3, off, 64);
        p4 += __shfl_xor(p4, off, 64);
        p5 += __shfl_xor(p5, off, 64);
    }
    int bucket = (p0 > 0.f ? 1 : 0) | (p1 > 0.f ? 2 : 0) | (p2 > 0.f ? 4 : 0) |
                 (p3 > 0.f ? 8 : 0) | (p4 > 0.f ? 16 : 0) | (p5 > 0.f ? 32 : 0);
    if (lane == 0) dst[wid] = bucket;
}

// ---- Phase 2a: histogram + scan per (side,bh). 32 blocks x 256 threads.
__global__ __launch_bounds__(256) void lsh_count_scan(const int* __restrict__ qbuckets,
                                                      const int* __restrict__ kbuckets,
                                                      int* __restrict__ kstart_packed, // [BH][NB] ks|cnt<<16
                                                      int* __restrict__ cur_q,         // [BH][NB]
                                                      int* __restrict__ cur_k) {       // [BH][NB]
    __shared__ int hist[NB];
    const int which = blockIdx.x >> 4;   // 0 = Q, 1 = K
    const int bh    = blockIdx.x & 15;
    const int tid   = threadIdx.x;
    const int* src  = (which ? kbuckets : qbuckets) + bh * S_LEN;

    if (tid < NB) hist[tid] = 0;
    __syncthreads();
#pragma unroll
    for (int i = 0; i < 8; ++i)
        atomicAdd(&hist[src[i * 256 + tid]], 1);   // coalesced reads
    __syncthreads();

    if (tid < 64) {   // wave 0: shuffle-scan the 64 bucket counts
        const int cnt = hist[tid];
        const int v   = which ? cnt : ((cnt + QPAD - 1) & ~(QPAD - 1));
        int x = v;
#pragma unroll
        for (int off = 1; off < 64; off <<= 1) {
            const int y = __shfl_up(x, off, 64);
            if (tid >= off) x += y;
        }
        const int start = x - v;   // exclusive prefix
        if (which) {
            kstart_packed[bh * NB + tid] = start | (cnt << 16);
            cur_k[bh * NB + tid] = start;
        } else {
            cur_q[bh * NB + tid] = start;
        }
    }
}

// ---- Phase 2c: scatter. Thread per element (2 sides x BH x S).
__global__ __launch_bounds__(256) void lsh_place(const int* __restrict__ qbuckets,
                                                 const int* __restrict__ kbuckets,
                                                 int* __restrict__ cur_q,
                                                 int* __restrict__ cur_k,
                                                 int* __restrict__ q_plist,
                                                 int* __restrict__ k_list) {
    const int gw    = blockIdx.x * 256 + threadIdx.x;   // 0 .. 2*BH*S-1
    const int which = gw >> 15;
    const int idx   = gw & (BH * S_LEN - 1);
    const int bh    = idx >> 11;
    const int i     = idx & (S_LEN - 1);
    if (which) {
        const int b    = kbuckets[idx];
        const int slot = atomicAdd(&cur_k[bh * NB + b], 1);
        k_list[bh * S_LEN + slot] = i;
    } else {
        const int b    = qbuckets[idx];
        const int slot = atomicAdd(&cur_q[bh * NB + b], 1);
        q_plist[bh * PADQ + slot] = i | (b << 16);
    }
}

// ---- Phase 3: wave per 4 same-bucket queries, 32-key chunks, half-wave D-split.
__global__ __launch_bounds__(256) void lsh_attn_d(const float* __restrict__ Q,
                                                  const float* __restrict__ K,
                                                  const float* __restrict__ V,
                                                  const int* __restrict__ q_plist,
                                                  const int* __restrict__ kstart_packed,
                                                  const int* __restrict__ k_list,
                                                  float* __restrict__ out) {
    __shared__ float qlds[4][QPAD][64];   // staged Q rows, per wave
    __shared__ float wbuf[4][QPAD][KCH];  // exp weights, per wave
    __shared__ int   kbuf[4][KCH];        // key indices, per wave

    const int wv   = threadIdx.x >> 6;
    const int lane = threadIdx.x & 63;
    const int h    = lane >> 5;           // dim-half / query-pair owner
    const int kk   = lane & 31;           // key slot within chunk
    const int bh   = blockIdx.y;
    // interleave: block b gets groups {b, b+140, b+280, b+420} -> mixed sizes
    const int grp  = blockIdx.x + wv * NBLK;

    const int4 dqv = *(const int4*)(q_plist + bh * PADQ + 4 * grp);
    const int e0 = __builtin_amdgcn_readfirstlane(dqv.x);
    if (e0 < 0) return;                   // all-sentinel group
    const int bucket = e0 >> 16;
    const int e1 = __builtin_amdgcn_readfirstlane(dqv.y);
    const int e2 = __builtin_amdgcn_readfirstlane(dqv.z);
    const int e3 = __builtin_amdgcn_readfirstlane(dqv.w);
    const int ksnk = __builtin_amdgcn_readfirstlane(kstart_packed[bh * NB + bucket]);
    const int ks = ksnk & 0xFFFF;
    const int nk = ksnk >> 16;

    const int q0 = e0 & 0xFFFF;
    const bool v1 = e1 >= 0, v2 = e2 >= 0, v3 = e3 >= 0;
    const int q1 = v1 ? (e1 & 0xFFFF) : q0;
    const int q2 = v2 ? (e2 & 0xFFFF) : q0;
    const int q3 = v3 ? (e3 & 0xFFFF) : q0;

    float* outb = out + (size_t)bh * S_LEN * D;
    if (nk == 0) {   // empty key bucket -> zero rows
        outb[(size_t)q0 * D + lane] = 0.0f;
        if (v1) outb[(size_t)q1 * D + lane] = 0.0f;
        if (v2) outb[(size_t)q2 * D + lane] = 0.0f;
        if (v3) outb[(size_t)q3 * D + lane] = 0.0f;
        return;
    }

    const int* kl   = k_list + bh * S_LEN + ks;
    const float* Kb = K + (size_t)bh * S_LEN * D;
    const float* Vb = V + (size_t)bh * S_LEN * D;
    const float* Qb = Q + (size_t)bh * S_LEN * D;

    // stage the 4 Q rows into per-wave LDS (coalesced; same-wave RAW is ordered)
    qlds[wv][0][lane] = Qb[(size_t)q0 * D + lane];
    qlds[wv][1][lane] = Qb[(size_t)q1 * D + lane];
    qlds[wv][2][lane] = Qb[(size_t)q2 * D + lane];
    qlds[wv][3][lane] = Qb[(size_t)q3 * D + lane];

    float l0 = 0.f, l1 = 0.f;             // this lane's 2 owned queries (2h, 2h+1)
    float acc[QPAD] = {0.f, 0.f, 0.f, 0.f};

    for (int c = 0; c * KCH < nk; ++c) {
        const int cnk  = min(KCH, nk - c * KCH);
        const int kidx = kl[c * KCH + min(kk, cnk - 1)];    // coalesced, clamped
        const float* krow = Kb + (size_t)kidx * D + h * 32; // this lane's dim-half

        // ---- K half-row resident in registers: 8 gathers issued back-to-back
        float4 kv[8];
#pragma unroll
        for (int i = 0; i < 8; ++i) kv[i] = *(const float4*)(krow + i * 4);

        // ---- partial scores over dim-half h for ALL 4 queries at key kk
        float s[QPAD];
#pragma unroll
        for (int j = 0; j < QPAD; ++j) {
            const float* qj = &qlds[wv][j][h * 32];
            float sj = 0.f;
#pragma unroll
            for (int i = 0; i < 8; ++i) {
                const float4 qv = *(const float4*)(qj + i * 4);   // LDS broadcast
                sj += qv.x * kv[i].x + qv.y * kv[i].y + qv.z * kv[i].z + qv.w * kv[i].w;
            }
            s[j] = sj;
        }
        // combine the two dim-halves (same key kk lives in lanes kk and kk+32)
        s[0] += __shfl_xor(s[0], 32, 64);
        s[1] += __shfl_xor(s[1], 32, 64);
        s[2] += __shfl_xor(s[2], 32, 64);
        s[3] += __shfl_xor(s[3], 32, 64);

        // ---- each half owns 2 queries: exp + linear l accumulation
        const bool kvalid = kk < cnk;
        const float sa = h ? s[2] : s[0];
        const float sb = h ? s[3] : s[1];
        const float ea = kvalid ? __expf(sa * 0.125f) : 0.f;
        const float eb = kvalid ? __expf(sb * 0.125f) : 0.f;
        l0 += ea;
        l1 += eb;
        wbuf[wv][2 * h + 0][kk] = ea;
        wbuf[wv][2 * h + 1][kk] = eb;
        if (h == 0) kbuf[wv][kk] = kidx;
        // same-wave LDS RAW: compiler inserts lgkmcnt wait

        // ---- PV: lane = dim; V rows shared by 4 queries
        const int ng = (cnk + 3) >> 2;
        for (int g = 0; g < ng; ++g) {
            const int4 kx = *(const int4*)&kbuf[wv][g * 4];
            const float vx = Vb[(size_t)kx.x * D + lane];
            const float vy = Vb[(size_t)kx.y * D + lane];
            const float vz = Vb[(size_t)kx.z * D + lane];
            const float vw = Vb[(size_t)kx.w * D + lane];
            const float4 eA = *(const float4*)&wbuf[wv][0][g * 4];
            const float4 eB = *(const float4*)&wbuf[wv][1][g * 4];
            const float4 eC = *(const float4*)&wbuf[wv][2][g * 4];
            const float4 eD = *(const float4*)&wbuf[wv][3][g * 4];
            acc[0] += eA.x * vx + eA.y * vy + eA.z * vz + eA.w * vw;
            acc[1] += eB.x * vx + eB.y * vy + eB.z * vz + eB.w * vw;
            acc[2] += eC.x * vx + eC.y * vy + eC.z * vz + eC.w * vw;
            acc[3] += eD.x * vx + eD.y * vy + eD.z * vz + eD.w * vw;
        }
    }

    // reduce l within each 32-lane half (owned queries), then swap halves
#pragma unroll
    for (int off = 16; off >= 1; off >>= 1) {
        l0 += __shfl_xor(l0, off, 64);
        l1 += __shfl_xor(l1, off, 64);
    }
    const float o0 = __shfl_xor(l0, 32, 64);
    const float o1 = __shfl_xor(l1, 32, 64);
    const float lq0 = h ? o0 : l0;
    const float lq1 = h ? o1 : l1;
    const float lq2 = h ? l0 : o0;
    const float lq3 = h ? l1 : o1;

    const float inv6 = 1.0f / 6.0f;
    outb[(size_t)q0 * D + lane] = acc[0] / (lq0 + 1e-8f) * inv6;
    if (v1) outb[(size_t)q1 * D + lane] = acc[1] / (lq1 + 1e-8f) * inv6;
    if (v2) outb[(size_t)q2 * D + lane] = acc[2] / (lq2 + 1e-8f) * inv6;
    if (v3) outb[(size_t)q3 * D + lane] = acc[3] / (lq3 + 1e-8f) * inv6;
}

extern "C" void kernel_launch(void* const* d_in, const int* in_sizes, int n_in,
                              void* d_out, int out_size, void* d_ws, size_t ws_size,
                              hipStream_t stream) {
    const float* Q   = (const float*)d_in[0];
    const float* K   = (const float*)d_in[1];
    const float* V   = (const float*)d_in[2];
    const float* rot = (const float*)d_in[3];
    float* out = (float*)d_out;

    char* ws = (char*)d_ws;
    int* q_buckets     = (int*)(ws);              // 128 KB
    int* k_buckets     = (int*)(ws + 131072);     // 128 KB
    int* k_list        = (int*)(ws + 262144);     // 128 KB
    int* q_plist       = (int*)(ws + 393216);     // 16*2240*4 = 140 KB (pad to 144K)
    int* kstart_packed = (int*)(ws + 540672);     // 4 KB
    int* cur_q         = (int*)(ws + 544768);     // 4 KB
    int* cur_k         = (int*)(ws + 548864);     // 4 KB

    lsh_buckets2<<<2 * BH * S_LEN / 4, 256, 0, stream>>>(Q, K, rot, q_buckets, k_buckets);
    lsh_count_scan<<<32, 256, 0, stream>>>(q_buckets, k_buckets, kstart_packed, cur_q, cur_k);
    hipMemsetAsync(q_plist, 0xFF, BH * PADQ * sizeof(int), stream);  // sentinel prefill
    lsh_place<<<2 * BH * S_LEN / 256, 256, 0, stream>>>(q_buckets, k_buckets, cur_q, cur_k,
                                                        q_plist, k_list);
    lsh_attn_d<<<dim3(NBLK, BH), 256, 0, stream>>>(Q, K, V, q_plist, kstart_packed,
                                                   k_list, out);
}

// Round 11
// 73.458 us; speedup vs baseline: 1.1362x; 1.1362x over previous
//
#include <hip/hip_runtime.h>
#include <math.h>

// LSH attention: B=2, H=8, S=2048, D=64, 6 bits -> 64 buckets, exact-match.
// 3 dispatches:
//  1) lsh_buckets2: bucket codes for Q and K (sign of X.rot)
//  2) lsh_sortfuse: per (side,bh) block: LDS histogram -> wave scan ->
//     sentinel fill -> LDS-cursor atomic scatter (order within bucket is
//     arbitrary; only ulp-level rounding differences)
//  3) lsh_attn_d: wave per 4 same-bucket queries (block-contiguous groups for
//     L1/L2 locality); 32-key chunks, half-wave D-split scores, kv[8]-resident
//     K half-row; no-max softmax; lane=dim PV.

constexpr int S_LEN = 2048;
constexpr int D = 64;
constexpr int NHASH = 6;
constexpr int BH = 16;     // B*H
constexpr int NB = 64;     // 2^NHASH
constexpr int QPAD = 4;    // queries per wave
constexpr int PADQ = S_LEN + (QPAD - 1) * NB;   // 2240
constexpr int NGRP = PADQ / QPAD;               // 560 wave-groups per bh
constexpr int NBLK = NGRP / 4;                  // 140 blocks per bh (4 waves each)
constexpr int KCH = 32;    // key-chunk width (matches ~32-key buckets)

// ---- Phase 1: bucket codes for Q and K in one dispatch. One wave per vector.
__global__ __launch_bounds__(256) void lsh_buckets2(const float* __restrict__ Q,
                                                    const float* __restrict__ K,
                                                    const float* __restrict__ rot,
                                                    int* __restrict__ qb,
                                                    int* __restrict__ kb) {
    const int gw   = (blockIdx.x * 256 + threadIdx.x) >> 6;
    const int lane = threadIdx.x & 63;
    const bool isK = gw >= BH * S_LEN;
    const int wid  = isK ? gw - BH * S_LEN : gw;
    const float* X = isK ? K : Q;
    int* dst       = isK ? kb : qb;
    const int h    = (wid >> 11) & 7;

    const float x  = X[(size_t)wid * D + lane];
    const float* r = rot + (size_t)h * NHASH * D + lane;
    float p0 = x * r[0 * D], p1 = x * r[1 * D], p2 = x * r[2 * D];
    float p3 = x * r[3 * D], p4 = x * r[4 * D], p5 = x * r[5 * D];
#pragma unroll
    for (int off = 32; off >= 1; off >>= 1) {
        p0 += __shfl_xor(p0, off, 64);
        p1 += __shfl_xor(p1, off, 64);
        p2 += __shfl_xor(p2, off, 64);
        p3 += __shfl_xor(p3, off, 64);
        p4 += __shfl_xor(p4, off, 64);
        p5 += __shfl_xor(p5, off, 64);
    }
    int bucket = (p0 > 0.f ? 1 : 0) | (p1 > 0.f ? 2 : 0) | (p2 > 0.f ? 4 : 0) |
                 (p3 > 0.f ? 8 : 0) | (p4 > 0.f ? 16 : 0) | (p5 > 0.f ? 32 : 0);
    if (lane == 0) dst[wid] = bucket;
}

// ---- Phase 2: fused count + scan + sentinel fill + scatter.
// One block per (side, bh): 32 blocks x 256 threads.
__global__ __launch_bounds__(256) void lsh_sortfuse(const int* __restrict__ qbuckets,
                                                    const int* __restrict__ kbuckets,
                                                    int* __restrict__ q_plist,       // [BH][PADQ]
                                                    int* __restrict__ kstart_packed, // [BH][NB] ks|cnt<<16
                                                    int* __restrict__ k_list) {      // [BH][S]
    __shared__ int hist[NB];
    __shared__ int start[NB];
    __shared__ int cur[NB];
    __shared__ int total;
    const int which = blockIdx.x >> 4;   // 0 = Q (padded), 1 = K
    const int bh    = blockIdx.x & 15;
    const int tid   = threadIdx.x;
    const int* src  = (which ? kbuckets : qbuckets) + bh * S_LEN;

    if (tid < NB) hist[tid] = 0;
    __syncthreads();

    int myb[8];
#pragma unroll
    for (int i = 0; i < 8; ++i) {
        myb[i] = src[i * 256 + tid];     // coalesced
        atomicAdd(&hist[myb[i]], 1);
    }
    __syncthreads();

    if (tid < NB) {   // wave 0: shuffle-scan the 64 bucket sizes
        const int cnt = hist[tid];
        const int v   = which ? cnt : ((cnt + QPAD - 1) & ~(QPAD - 1));
        int x = v;
#pragma unroll
        for (int off = 1; off < 64; off <<= 1) {
            const int y = __shfl_up(x, off, 64);
            if (tid >= off) x += y;
        }
        const int st = x - v;            // exclusive prefix
        start[tid] = st;
        cur[tid]   = st;
        if (which) kstart_packed[bh * NB + tid] = st | (cnt << 16);
        if (tid == 63) total = x;        // total padded length (q side)
    }
    __syncthreads();

    if (!which) {
        int* qp = q_plist + bh * PADQ;
        // per-bucket pad sentinels (<=3 each) + tail sentinels
        if (tid < NB) {
            const int cnt    = hist[tid];
            const int padded = (cnt + QPAD - 1) & ~(QPAD - 1);
            for (int t = start[tid] + cnt; t < start[tid] + padded; ++t) qp[t] = -1;
        }
        for (int t = total + tid; t < PADQ; t += 256) qp[t] = -1;
        // scatter (LDS cursor atomics; within-bucket order arbitrary)
#pragma unroll
        for (int i = 0; i < 8; ++i) {
            const int b    = myb[i];
            const int slot = atomicAdd(&cur[b], 1);
            qp[slot] = (i * 256 + tid) | (b << 16);
        }
    } else {
        int* klp = k_list + bh * S_LEN;
#pragma unroll
        for (int i = 0; i < 8; ++i) {
            const int b    = myb[i];
            const int slot = atomicAdd(&cur[b], 1);
            klp[slot] = i * 256 + tid;
        }
    }
}

// ---- Phase 3: wave per 4 same-bucket queries, 32-key chunks, half-wave D-split.
__global__ __launch_bounds__(256) void lsh_attn_d(const float* __restrict__ Q,
                                                  const float* __restrict__ K,
                                                  const float* __restrict__ V,
                                                  const int* __restrict__ q_plist,
                                                  const int* __restrict__ kstart_packed,
                                                  const int* __restrict__ k_list,
                                                  float* __restrict__ out) {
    __shared__ float qlds[4][QPAD][64];   // staged Q rows, per wave
    __shared__ float wbuf[4][QPAD][KCH];  // exp weights, per wave
    __shared__ int   kbuf[4][KCH];        // key indices, per wave

    const int wv   = threadIdx.x >> 6;
    const int lane = threadIdx.x & 63;
    const int h    = lane >> 5;           // dim-half / query-pair owner
    const int kk   = lane & 31;           // key slot within chunk
    const int bh   = blockIdx.y;
    const int grp  = blockIdx.x * 4 + wv; // block-contiguous groups: L1/L2 reuse

    const int* pl = q_plist + bh * PADQ + 4 * grp;
    const int e0 = __builtin_amdgcn_readfirstlane(pl[0]);
    if (e0 < 0) return;                   // all-sentinel group
    const int bucket = e0 >> 16;
    const int e1 = __builtin_amdgcn_readfirstlane(pl[1]);
    const int e2 = __builtin_amdgcn_readfirstlane(pl[2]);
    const int e3 = __builtin_amdgcn_readfirstlane(pl[3]);
    const int ksnk = __builtin_amdgcn_readfirstlane(kstart_packed[bh * NB + bucket]);
    const int ks = ksnk & 0xFFFF;
    const int nk = ksnk >> 16;

    const int q0 = e0 & 0xFFFF;
    const bool v1 = e1 >= 0, v2 = e2 >= 0, v3 = e3 >= 0;
    const int q1 = v1 ? (e1 & 0xFFFF) : q0;
    const int q2 = v2 ? (e2 & 0xFFFF) : q0;
    const int q3 = v3 ? (e3 & 0xFFFF) : q0;

    float* outb = out + (size_t)bh * S_LEN * D;
    if (nk == 0) {   // empty key bucket -> zero rows
        outb[(size_t)q0 * D + lane] = 0.0f;
        if (v1) outb[(size_t)q1 * D + lane] = 0.0f;
        if (v2) outb[(size_t)q2 * D + lane] = 0.0f;
        if (v3) outb[(size_t)q3 * D + lane] = 0.0f;
        return;
    }

    const int* kl   = k_list + bh * S_LEN + ks;
    const float* Kb = K + (size_t)bh * S_LEN * D;
    const float* Vb = V + (size_t)bh * S_LEN * D;
    const float* Qb = Q + (size_t)bh * S_LEN * D;

    // stage the 4 Q rows into per-wave LDS (coalesced; same-wave RAW is ordered)
    qlds[wv][0][lane] = Qb[(size_t)q0 * D + lane];
    qlds[wv][1][lane] = Qb[(size_t)q1 * D + lane];
    qlds[wv][2][lane] = Qb[(size_t)q2 * D + lane];
    qlds[wv][3][lane] = Qb[(size_t)q3 * D + lane];

    float l0 = 0.f, l1 = 0.f;             // this lane's 2 owned queries (2h, 2h+1)
    float acc[QPAD] = {0.f, 0.f, 0.f, 0.f};

    for (int c = 0; c * KCH < nk; ++c) {
        const int cnk  = min(KCH, nk - c * KCH);
        const int kidx = kl[c * KCH + min(kk, cnk - 1)];    // coalesced, clamped
        const float* krow = Kb + (size_t)kidx * D + h * 32; // this lane's dim-half

        // ---- K half-row resident in registers: 8 gathers issued back-to-back
        float4 kv[8];
#pragma unroll
        for (int i = 0; i < 8; ++i) kv[i] = *(const float4*)(krow + i * 4);

        // ---- partial scores over dim-half h for ALL 4 queries at key kk
        float s[QPAD];
#pragma unroll
        for (int j = 0; j < QPAD; ++j) {
            const float* qj = &qlds[wv][j][h * 32];
            float sj = 0.f;
#pragma unroll
            for (int i = 0; i < 8; ++i) {
                const float4 qv = *(const float4*)(qj + i * 4);   // LDS broadcast
                sj += qv.x * kv[i].x + qv.y * kv[i].y + qv.z * kv[i].z + qv.w * kv[i].w;
            }
            s[j] = sj;
        }
        // combine the two dim-halves (same key kk lives in lanes kk and kk+32)
        s[0] += __shfl_xor(s[0], 32, 64);
        s[1] += __shfl_xor(s[1], 32, 64);
        s[2] += __shfl_xor(s[2], 32, 64);
        s[3] += __shfl_xor(s[3], 32, 64);

        // ---- each half owns 2 queries: exp + linear l accumulation
        const bool kvalid = kk < cnk;
        const float sa = h ? s[2] : s[0];
        const float sb = h ? s[3] : s[1];
        const float ea = kvalid ? __expf(sa * 0.125f) : 0.f;
        const float eb = kvalid ? __expf(sb * 0.125f) : 0.f;
        l0 += ea;
        l1 += eb;
        wbuf[wv][2 * h + 0][kk] = ea;
        wbuf[wv][2 * h + 1][kk] = eb;
        if (h == 0) kbuf[wv][kk] = kidx;
        // same-wave LDS RAW: compiler inserts lgkmcnt wait

        // ---- PV: lane = dim; V rows shared by 4 queries
        const int ng = (cnk + 3) >> 2;
        for (int g = 0; g < ng; ++g) {
            const int4 kx = *(const int4*)&kbuf[wv][g * 4];
            const float vx = Vb[(size_t)kx.x * D + lane];
            const float vy = Vb[(size_t)kx.y * D + lane];
            const float vz = Vb[(size_t)kx.z * D + lane];
            const float vw = Vb[(size_t)kx.w * D + lane];
            const float4 eA = *(const float4*)&wbuf[wv][0][g * 4];
            const float4 eB = *(const float4*)&wbuf[wv][1][g * 4];
            const float4 eC = *(const float4*)&wbuf[wv][2][g * 4];
            const float4 eD = *(const float4*)&wbuf[wv][3][g * 4];
            acc[0] += eA.x * vx + eA.y * vy + eA.z * vz + eA.w * vw;
            acc[1] += eB.x * vx + eB.y * vy + eB.z * vz + eB.w * vw;
            acc[2] += eC.x * vx + eC.y * vy + eC.z * vz + eC.w * vw;
            acc[3] += eD.x * vx + eD.y * vy + eD.z * vz + eD.w * vw;
        }
    }

    // reduce l within each 32-lane half (owned queries), then swap halves
#pragma unroll
    for (int off = 16; off >= 1; off >>= 1) {
        l0 += __shfl_xor(l0, off, 64);
        l1 += __shfl_xor(l1, off, 64);
    }
    const float o0 = __shfl_xor(l0, 32, 64);
    const float o1 = __shfl_xor(l1, 32, 64);
    const float lq0 = h ? o0 : l0;
    const float lq1 = h ? o1 : l1;
    const float lq2 = h ? l0 : o0;
    const float lq3 = h ? l1 : o1;

    const float inv6 = 1.0f / 6.0f;
    outb[(size_t)q0 * D + lane] = acc[0] / (lq0 + 1e-8f) * inv6;
    if (v1) outb[(size_t)q1 * D + lane] = acc[1] / (lq1 + 1e-8f) * inv6;
    if (v2) outb[(size_t)q2 * D + lane] = acc[2] / (lq2 + 1e-8f) * inv6;
    if (v3) outb[(size_t)q3 * D + lane] = acc[3] / (lq3 + 1e-8f) * inv6;
}

extern "C" void kernel_launch(void* const* d_in, const int* in_sizes, int n_in,
                              void* d_out, int out_size, void* d_ws, size_t ws_size,
                              hipStream_t stream) {
    const float* Q   = (const float*)d_in[0];
    const float* K   = (const float*)d_in[1];
    const float* V   = (const float*)d_in[2];
    const float* rot = (const float*)d_in[3];
    float* out = (float*)d_out;

    char* ws = (char*)d_ws;
    int* q_buckets     = (int*)(ws);              // 128 KB
    int* k_buckets     = (int*)(ws + 131072);     // 128 KB
    int* k_list        = (int*)(ws + 262144);     // 128 KB
    int* q_plist       = (int*)(ws + 393216);     // 16*2240*4 = 140 KB (pad to 144K)
    int* kstart_packed = (int*)(ws + 540672);     // 4 KB

    lsh_buckets2<<<2 * BH * S_LEN / 4, 256, 0, stream>>>(Q, K, rot, q_buckets, k_buckets);
    lsh_sortfuse<<<32, 256, 0, stream>>>(q_buckets, k_buckets, q_plist, kstart_packed, k_list);
    lsh_attn_d<<<dim3(NBLK, BH), 256, 0, stream>>>(Q, K, V, q_plist, kstart_packed,
                                                   k_list, out);
}

// Round 12
// 72.813 us; speedup vs baseline: 1.1462x; 1.0089x over previous
//
#include <hip/hip_runtime.h>
#include <math.h>

// LSH attention: B=2, H=8, S=2048, D=64, 6 bits -> 64 buckets, exact-match.
// 3 dispatches:
//  1) lsh_buckets2: bucket codes for Q and K (sign of X.rot)
//  2) lsh_sortfuse_bh: ONE block per bh, K pass then Q pass:
//     histogram -> wave scan -> scatter. Q-list entries carry the K-side
//     bucket info inline: e0 = q0 | ks<<16, e1 = q1|nk<<16 (q field 0xFFFF =
//     sentinel). Within-bucket order arbitrary (ulp-level rounding only).
//  3) lsh_attn_d: wave per 4 same-bucket queries; 1-D grid with XCD-pinning
//     decode (each XCD serves 2 bh -> K/V fits its 4MB L2); 32-key chunks,
//     half-wave D-split scores, kv[8]-resident K half-row; no-max softmax;
//     lane=dim PV.

constexpr int S_LEN = 2048;
constexpr int D = 64;
constexpr int NHASH = 6;
constexpr int BH = 16;     // B*H
constexpr int NB = 64;     // 2^NHASH
constexpr int QPAD = 4;    // queries per wave
constexpr int PADQ = S_LEN + (QPAD - 1) * NB;   // 2240
constexpr int NGRP = PADQ / QPAD;               // 560 wave-groups per bh
constexpr int NBLK = NGRP / 4;                  // 140 blocks per bh (4 waves each)
constexpr int KCH = 32;    // key-chunk width (matches ~32-key buckets)

// ---- Phase 1: bucket codes for Q and K in one dispatch. One wave per vector.
__global__ __launch_bounds__(256) void lsh_buckets2(const float* __restrict__ Q,
                                                    const float* __restrict__ K,
                                                    const float* __restrict__ rot,
                                                    int* __restrict__ qb,
                                                    int* __restrict__ kb) {
    const int gw   = (blockIdx.x * 256 + threadIdx.x) >> 6;
    const int lane = threadIdx.x & 63;
    const bool isK = gw >= BH * S_LEN;
    const int wid  = isK ? gw - BH * S_LEN : gw;
    const float* X = isK ? K : Q;
    int* dst       = isK ? kb : qb;
    const int h    = (wid >> 11) & 7;

    const float x  = X[(size_t)wid * D + lane];
    const float* r = rot + (size_t)h * NHASH * D + lane;
    float p0 = x * r[0 * D], p1 = x * r[1 * D], p2 = x * r[2 * D];
    float p3 = x * r[3 * D], p4 = x * r[4 * D], p5 = x * r[5 * D];
#pragma unroll
    for (int off = 32; off >= 1; off >>= 1) {
        p0 += __shfl_xor(p0, off, 64);
        p1 += __shfl_xor(p1, off, 64);
        p2 += __shfl_xor(p2, off, 64);
        p3 += __shfl_xor(p3, off, 64);
        p4 += __shfl_xor(p4, off, 64);
        p5 += __shfl_xor(p5, off, 64);
    }
    int bucket = (p0 > 0.f ? 1 : 0) | (p1 > 0.f ? 2 : 0) | (p2 > 0.f ? 4 : 0) |
                 (p3 > 0.f ? 8 : 0) | (p4 > 0.f ? 16 : 0) | (p5 > 0.f ? 32 : 0);
    if (lane == 0) dst[wid] = bucket;
}

// ---- Phase 2: fused per-bh sort. One block per bh (16 blocks x 256 threads).
// K pass first (k_list + kst/kcnt in LDS), then Q pass embedding ks/nk into
// the padded group entries.
__global__ __launch_bounds__(256) void lsh_sortfuse_bh(const int* __restrict__ qbuckets,
                                                       const int* __restrict__ kbuckets,
                                                       int* __restrict__ q_plist,  // [BH][PADQ]
                                                       int* __restrict__ k_list) { // [BH][S]
    __shared__ int hist[NB];
    __shared__ int cur[NB];
    __shared__ int kst[NB], kcnt[NB];
    __shared__ int qst[NB];
    __shared__ int total;
    const int bh  = blockIdx.x;
    const int tid = threadIdx.x;

    // ================= K pass =================
    if (tid < NB) hist[tid] = 0;
    __syncthreads();
    int myk[8];
#pragma unroll
    for (int i = 0; i < 8; ++i) {
        myk[i] = kbuckets[bh * S_LEN + i * 256 + tid];   // coalesced
        atomicAdd(&hist[myk[i]], 1);
    }
    __syncthreads();
    if (tid < NB) {   // wave 0: shuffle-scan the 64 bucket sizes
        const int cnt = hist[tid];
        int x = cnt;
#pragma unroll
        for (int off = 1; off < 64; off <<= 1) {
            const int y = __shfl_up(x, off, 64);
            if (tid >= off) x += y;
        }
        kst[tid]  = x - cnt;
        kcnt[tid] = cnt;
        cur[tid]  = x - cnt;
    }
    __syncthreads();
    {
        int* klp = k_list + bh * S_LEN;
#pragma unroll
        for (int i = 0; i < 8; ++i) {
            const int b    = myk[i];
            const int slot = atomicAdd(&cur[b], 1);
            klp[slot] = i * 256 + tid;
        }
    }
    __syncthreads();

    // ================= Q pass =================
    if (tid < NB) hist[tid] = 0;
    __syncthreads();
    int myq[8];
#pragma unroll
    for (int i = 0; i < 8; ++i) {
        myq[i] = qbuckets[bh * S_LEN + i * 256 + tid];
        atomicAdd(&hist[myq[i]], 1);
    }
    __syncthreads();
    if (tid < NB) {
        const int cnt = hist[tid];
        const int v   = (cnt + QPAD - 1) & ~(QPAD - 1);
        int x = v;
#pragma unroll
        for (int off = 1; off < 64; off <<= 1) {
            const int y = __shfl_up(x, off, 64);
            if (tid >= off) x += y;
        }
        qst[tid] = x - v;
        cur[tid] = x - v;
        if (tid == 63) total = x;
    }
    __syncthreads();

    int* qp = q_plist + bh * PADQ;
    // per-bucket pad sentinels (q-field 0xFFFF; keep nk in high bits for pos1)
    if (tid < NB) {
        const int cnt    = hist[tid];
        const int padded = (cnt + QPAD - 1) & ~(QPAD - 1);
        const int sent   = 0xFFFF | (kcnt[tid] << 16);
        for (int t = qst[tid] + cnt; t < qst[tid] + padded; ++t) qp[t] = sent;
    }
    for (int t = total + tid; t < PADQ; t += 256) qp[t] = -1;   // whole-group sentinel
    // scatter: entry layout depends on slot position within its group
#pragma unroll
    for (int i = 0; i < 8; ++i) {
        const int b    = myq[i];
        const int slot = atomicAdd(&cur[b], 1);
        const int pos  = slot & 3;
        int e = i * 256 + tid;
        if (pos == 0)      e |= kst[b] << 16;
        else if (pos == 1) e |= kcnt[b] << 16;
        qp[slot] = e;
    }
}

// ---- Phase 3: wave per 4 same-bucket queries, 32-key chunks, half-wave D-split.
// 1-D grid, XCD-pinned: w -> xcd=w&7, bh = (w&7)+8*((w>>3)&1), blk = w>>4.
__global__ __launch_bounds__(256) void lsh_attn_d(const float* __restrict__ Q,
                                                  const float* __restrict__ K,
                                                  const float* __restrict__ V,
                                                  const int* __restrict__ q_plist,
                                                  const int* __restrict__ k_list,
                                                  float* __restrict__ out) {
    __shared__ float qlds[4][QPAD][64];   // staged Q rows, per wave
    __shared__ float wbuf[4][QPAD][KCH];  // exp weights, per wave
    __shared__ int   kbuf[4][KCH];        // key indices, per wave

    const int wv   = threadIdx.x >> 6;
    const int lane = threadIdx.x & 63;
    const int h    = lane >> 5;           // dim-half / query-pair owner
    const int kk   = lane & 31;           // key slot within chunk
    const int w    = blockIdx.x;
    const int bh   = (w & 7) + 8 * ((w >> 3) & 1);   // XCD w&7 serves bh, bh+8
    const int blk  = w >> 4;
    const int grp  = blk * 4 + wv;        // block-contiguous groups: L1/L2 reuse

    const int* pl = q_plist + bh * PADQ + 4 * grp;
    const int e0 = __builtin_amdgcn_readfirstlane(pl[0]);
    if ((e0 & 0xFFFF) == 0xFFFF) return;  // all-sentinel group
    const int e1 = __builtin_amdgcn_readfirstlane(pl[1]);
    const int e2 = __builtin_amdgcn_readfirstlane(pl[2]);
    const int e3 = __builtin_amdgcn_readfirstlane(pl[3]);

    const int q0 = e0 & 0xFFFF;
    const int ks = (unsigned)e0 >> 16;
    const int nk = (unsigned)e1 >> 16;
    const int t1 = e1 & 0xFFFF, t2 = e2 & 0xFFFF, t3 = e3 & 0xFFFF;
    const bool v1 = t1 != 0xFFFF, v2 = t2 != 0xFFFF, v3 = t3 != 0xFFFF;
    const int q1 = v1 ? t1 : q0;
    const int q2 = v2 ? t2 : q0;
    const int q3 = v3 ? t3 : q0;

    float* outb = out + (size_t)bh * S_LEN * D;
    if (nk == 0) {   // empty key bucket -> zero rows
        outb[(size_t)q0 * D + lane] = 0.0f;
        if (v1) outb[(size_t)q1 * D + lane] = 0.0f;
        if (v2) outb[(size_t)q2 * D + lane] = 0.0f;
        if (v3) outb[(size_t)q3 * D + lane] = 0.0f;
        return;
    }

    const int* kl   = k_list + bh * S_LEN + ks;
    const float* Kb = K + (size_t)bh * S_LEN * D;
    const float* Vb = V + (size_t)bh * S_LEN * D;
    const float* Qb = Q + (size_t)bh * S_LEN * D;

    // stage the 4 Q rows into per-wave LDS (coalesced; same-wave RAW is ordered)
    qlds[wv][0][lane] = Qb[(size_t)q0 * D + lane];
    qlds[wv][1][lane] = Qb[(size_t)q1 * D + lane];
    qlds[wv][2][lane] = Qb[(size_t)q2 * D + lane];
    qlds[wv][3][lane] = Qb[(size_t)q3 * D + lane];

    float l0 = 0.f, l1 = 0.f;             // this lane's 2 owned queries (2h, 2h+1)
    float acc[QPAD] = {0.f, 0.f, 0.f, 0.f};

    for (int c = 0; c * KCH < nk; ++c) {
        const int cnk  = min(KCH, nk - c * KCH);
        const int kidx = kl[c * KCH + min(kk, cnk - 1)];    // coalesced, clamped
        const float* krow = Kb + (size_t)kidx * D + h * 32; // this lane's dim-half

        // ---- K half-row resident in registers: 8 gathers issued back-to-back
        float4 kv[8];
#pragma unroll
        for (int i = 0; i < 8; ++i) kv[i] = *(const float4*)(krow + i * 4);

        // ---- partial scores over dim-half h for ALL 4 queries at key kk
        float s[QPAD];
#pragma unroll
        for (int j = 0; j < QPAD; ++j) {
            const float* qj = &qlds[wv][j][h * 32];
            float sj = 0.f;
#pragma unroll
            for (int i = 0; i < 8; ++i) {
                const float4 qv = *(const float4*)(qj + i * 4);   // LDS broadcast
                sj += qv.x * kv[i].x + qv.y * kv[i].y + qv.z * kv[i].z + qv.w * kv[i].w;
            }
            s[j] = sj;
        }
        // combine the two dim-halves (same key kk lives in lanes kk and kk+32)
        s[0] += __shfl_xor(s[0], 32, 64);
        s[1] += __shfl_xor(s[1], 32, 64);
        s[2] += __shfl_xor(s[2], 32, 64);
        s[3] += __shfl_xor(s[3], 32, 64);

        // ---- each half owns 2 queries: exp + linear l accumulation
        const bool kvalid = kk < cnk;
        const float sa = h ? s[2] : s[0];
        const float sb = h ? s[3] : s[1];
        const float ea = kvalid ? __expf(sa * 0.125f) : 0.f;
        const float eb = kvalid ? __expf(sb * 0.125f) : 0.f;
        l0 += ea;
        l1 += eb;
        wbuf[wv][2 * h + 0][kk] = ea;
        wbuf[wv][2 * h + 1][kk] = eb;
        if (h == 0) kbuf[wv][kk] = kidx;
        // same-wave LDS RAW: compiler inserts lgkmcnt wait

        // ---- PV: lane = dim; V rows shared by 4 queries
        const int ng = (cnk + 3) >> 2;
        for (int g = 0; g < ng; ++g) {
            const int4 kx = *(const int4*)&kbuf[wv][g * 4];
            const float vx = Vb[(size_t)kx.x * D + lane];
            const float vy = Vb[(size_t)kx.y * D + lane];
            const float vz = Vb[(size_t)kx.z * D + lane];
            const float vw = Vb[(size_t)kx.w * D + lane];
            const float4 eA = *(const float4*)&wbuf[wv][0][g * 4];
            const float4 eB = *(const float4*)&wbuf[wv][1][g * 4];
            const float4 eC = *(const float4*)&wbuf[wv][2][g * 4];
            const float4 eD = *(const float4*)&wbuf[wv][3][g * 4];
            acc[0] += eA.x * vx + eA.y * vy + eA.z * vz + eA.w * vw;
            acc[1] += eB.x * vx + eB.y * vy + eB.z * vz + eB.w * vw;
            acc[2] += eC.x * vx + eC.y * vy + eC.z * vz + eC.w * vw;
            acc[3] += eD.x * vx + eD.y * vy + eD.z * vz + eD.w * vw;
        }
    }

    // reduce l within each 32-lane half (owned queries), then swap halves
#pragma unroll
    for (int off = 16; off >= 1; off >>= 1) {
        l0 += __shfl_xor(l0, off, 64);
        l1 += __shfl_xor(l1, off, 64);
    }
    const float o0 = __shfl_xor(l0, 32, 64);
    const float o1 = __shfl_xor(l1, 32, 64);
    const float lq0 = h ? o0 : l0;
    const float lq1 = h ? o1 : l1;
    const float lq2 = h ? l0 : o0;
    const float lq3 = h ? l1 : o1;

    const float inv6 = 1.0f / 6.0f;
    outb[(size_t)q0 * D + lane] = acc[0] / (lq0 + 1e-8f) * inv6;
    if (v1) outb[(size_t)q1 * D + lane] = acc[1] / (lq1 + 1e-8f) * inv6;
    if (v2) outb[(size_t)q2 * D + lane] = acc[2] / (lq2 + 1e-8f) * inv6;
    if (v3) outb[(size_t)q3 * D + lane] = acc[3] / (lq3 + 1e-8f) * inv6;
}

extern "C" void kernel_launch(void* const* d_in, const int* in_sizes, int n_in,
                              void* d_out, int out_size, void* d_ws, size_t ws_size,
                              hipStream_t stream) {
    const float* Q   = (const float*)d_in[0];
    const float* K   = (const float*)d_in[1];
    const float* V   = (const float*)d_in[2];
    const float* rot = (const float*)d_in[3];
    float* out = (float*)d_out;

    char* ws = (char*)d_ws;
    int* q_buckets = (int*)(ws);              // 128 KB
    int* k_buckets = (int*)(ws + 131072);     // 128 KB
    int* k_list    = (int*)(ws + 262144);     // 128 KB
    int* q_plist   = (int*)(ws + 393216);     // 16*2240*4 = 140 KB

    lsh_buckets2<<<2 * BH * S_LEN / 4, 256, 0, stream>>>(Q, K, rot, q_buckets, k_buckets);
    lsh_sortfuse_bh<<<BH, 256, 0, stream>>>(q_buckets, k_buckets, q_plist, k_list);
    lsh_attn_d<<<NBLK * BH, 256, 0, stream>>>(Q, K, V, q_plist, k_list, out);
}